// Round 1
// baseline (858.487 us; speedup 1.0000x reference)
//
#include <hip/hip_runtime.h>

#define EPS 1e-5f
#define B 8
#define C 256
#define NPIX 4096      // 64*64
#define NCH 144        // rows: 0..63 q_bn, 64..127 v_bn, 128..143 kf(raw)
#define ROW_V 64
#define ROW_KF 128
#define PAD 11

// workspace layout (float offsets)
#define WP_OFF    0u          // 144*256 = 36864
#define BIAS_OFF  36864u      // 144
#define PROJ_OFF  37120u      // 8*144*4096 = 4718592
#define RMAX_OFF  4755712u    // 128
#define RSC_OFF   4755840u    // 128
#define LC_OFF    4755968u    // 8*16*64 = 8192   (end 4764160 floats = 19.06 MB)

// ---------------- 1) fold BN into combined projection weights ----------------
__global__ __launch_bounds__(256) void k_wfold(
    const float* __restrict__ Wq, const float* __restrict__ qg, const float* __restrict__ qb,
    const float* __restrict__ qm, const float* __restrict__ qv,
    const float* __restrict__ Wk, const float* __restrict__ Wv,
    const float* __restrict__ vg, const float* __restrict__ vb,
    const float* __restrict__ vm, const float* __restrict__ vvar,
    float* __restrict__ Wp, float* __restrict__ biasp) {
  int o = blockIdx.x;   // 0..143
  int t = threadIdx.x;  // 0..255 = c
  const float* src; float s, bias;
  if (o < 64) {
    s = qg[o] * rsqrtf(qv[o] + EPS); bias = qb[o] - qm[o] * s; src = Wq + o * C;
  } else if (o < 128) {
    int i = o - 64;
    s = vg[i] * rsqrtf(vvar[i] + EPS); bias = vb[i] - vm[i] * s; src = Wv + i * C;
  } else {
    int i = o - 128; s = 1.f; bias = 0.f; src = Wk + i * C;
  }
  Wp[o * C + t] = src[t] * s;
  if (t == 0) biasp[o] = bias;
}

// ---------------- 2) projection GEMM: proj[b][o][n] = sum_c W'[o][c] x[b][c][n] + b'[o] ----
__global__ __launch_bounds__(256) void k_proj(
    const float* __restrict__ x, const float* __restrict__ Wp,
    const float* __restrict__ biasp, float* __restrict__ proj) {
  int g = blockIdx.x;     // channel group 0..8 (16 ch each)
  int tile = blockIdx.y;  // 0..15 (256 px each)
  int b = blockIdx.z;
  int t = threadIdx.x;
  int px = tile * 256 + t;
  const float* xb = x + (size_t)b * C * NPIX + px;
  const float* wbase = Wp + g * 16 * C;   // wave-uniform accesses below
  float acc[16];
  #pragma unroll
  for (int i = 0; i < 16; i++) acc[i] = 0.f;
  #pragma unroll 4
  for (int c = 0; c < C; c++) {
    float xv = xb[(size_t)c * NPIX];
    #pragma unroll
    for (int i = 0; i < 16; i++) acc[i] += xv * wbase[i * C + c];
  }
  float* ob = proj + ((size_t)b * NCH + g * 16) * NPIX + px;
  #pragma unroll
  for (int i = 0; i < 16; i++) ob[(size_t)i * NPIX] = acc[i] + biasp[g * 16 + i];
}

// ---------------- 3) softmax row stats for kf rows ----------------
__global__ __launch_bounds__(256) void k_softstat(
    const float* __restrict__ proj, float* __restrict__ rmax, float* __restrict__ rsc) {
  int k = blockIdx.x, b = blockIdx.y, t = threadIdx.x;
  const float* row = proj + ((size_t)b * NCH + ROW_KF + k) * NPIX;
  __shared__ float sd[256];
  float m = -1e30f;
  for (int n = t; n < NPIX; n += 256) m = fmaxf(m, row[n]);
  sd[t] = m; __syncthreads();
  for (int s = 128; s > 0; s >>= 1) { if (t < s) sd[t] = fmaxf(sd[t], sd[t + s]); __syncthreads(); }
  m = sd[0]; __syncthreads();
  float sum = 0.f;
  for (int n = t; n < NPIX; n += 256) sum += __expf(row[n] - m);
  sd[t] = sum; __syncthreads();
  for (int s = 128; s > 0; s >>= 1) { if (t < s) sd[t] += sd[t + s]; __syncthreads(); }
  if (t == 0) { rmax[b * 16 + k] = m; rsc[b * 16 + k] = 1.f / sd[0]; }
}

// ---------------- 4) lambda_c[b][k][v] = sum_n softmax(kf)[b,k,n] * v_bn[b,v,n] ----------
__global__ __launch_bounds__(256) void k_lambda_c(
    const float* __restrict__ proj, const float* __restrict__ rmax,
    const float* __restrict__ rsc, float* __restrict__ lc) {
  int k = blockIdx.x, b = blockIdx.y, t = threadIdx.x;
  const float* row = proj + ((size_t)b * NCH + ROW_KF + k) * NPIX;
  const float* vbase = proj + ((size_t)b * NCH + ROW_V) * NPIX;
  float m = rmax[b * 16 + k], sc = rsc[b * 16 + k];
  float acc[64];
  #pragma unroll
  for (int i = 0; i < 64; i++) acc[i] = 0.f;
  for (int it = 0; it < 16; ++it) {
    int n = it * 256 + t;
    float p = __expf(row[n] - m) * sc;
    #pragma unroll
    for (int vv = 0; vv < 64; vv++) acc[vv] += p * vbase[(size_t)vv * NPIX + n];
  }
  // reduce across 256 threads: wave shuffle, then 4 partials via LDS
  int lane = t & 63, wid = t >> 6;
  float keep = 0.f;
  #pragma unroll
  for (int vv = 0; vv < 64; vv++) {
    float s = acc[vv];
    #pragma unroll
    for (int off = 32; off > 0; off >>= 1) s += __shfl_xor(s, off);
    if (lane == vv) keep = s;
  }
  __shared__ float sh[4 * 64];
  sh[wid * 64 + lane] = keep;
  __syncthreads();
  if (t < 64)
    lc[((size_t)b * 16 + k) * 64 + t] = sh[t] + sh[64 + t] + sh[128 + t] + sh[192 + t];
}

// ---------------- 5) fused 23x23 conv (lambda_p) + k-contraction with q + y_c -----------
#define VH_PITCH 88
#define VH_ROWS 38
__global__ __launch_bounds__(256) void k_conv_fused(
    const float* __restrict__ proj, const float* __restrict__ emb,
    const float* __restrict__ lc, float* __restrict__ out) {
  int v = blockIdx.x;     // 0..63  (fastest: blocks sharing (b,tile) reuse q tile in L2)
  int tile = blockIdx.y;  // 0..3   (16 image rows each)
  int b = blockIdx.z;
  int t = threadIdx.x;
  __shared__ float es[16 * 529];
  __shared__ float vh[VH_ROWS * VH_PITCH];
  for (int i = t; i < 16 * 529; i += 256) es[i] = emb[i];
  int r0 = tile * 16;
  const float* vrow = proj + ((size_t)b * NCH + ROW_V + v) * NPIX;
  for (int i = t; i < VH_ROWS * 86; i += 256) {
    int r = i / 86, cc = i % 86;
    int gr = r0 + r - PAD, gc = cc - PAD;
    float val = 0.f;
    if (gr >= 0 && gr < 64 && gc >= 0 && gc < 64) val = vrow[gr * 64 + gc];
    vh[r * VH_PITCH + cc] = val;
  }
  __syncthreads();
  int col = t & 63, rq = t >> 6;  // thread covers 4 rows (rq*4..rq*4+3) at this col
  float lp[16][4];
  #pragma unroll
  for (int k = 0; k < 16; k++)
    #pragma unroll
    for (int i = 0; i < 4; i++) lp[k][i] = 0.f;
  for (int ky = 0; ky < 23; ky++) {
    for (int kx = 0; kx < 23; kx++) {
      float ev[16];
      #pragma unroll
      for (int k = 0; k < 16; k++) ev[k] = es[k * 529 + ky * 23 + kx];  // LDS broadcast
      #pragma unroll
      for (int i = 0; i < 4; i++) {
        float vv = vh[(rq * 4 + i + ky) * VH_PITCH + col + kx];
        #pragma unroll
        for (int k = 0; k < 16; k++) lp[k][i] += vv * ev[k];
      }
    }
  }
  float lcv[16];
  #pragma unroll
  for (int k = 0; k < 16; k++) lcv[k] = lc[((size_t)b * 16 + k) * 64 + v];  // uniform
  const float* qb = proj + (size_t)b * NCH * NPIX;   // q rows 0..63, ch = h*16+k
  float* ob = out + (size_t)b * 256 * NPIX;
  #pragma unroll
  for (int i = 0; i < 4; i++) {
    int n = (r0 + rq * 4 + i) * 64 + col;
    float y0 = 0.f, y1 = 0.f, y2 = 0.f, y3 = 0.f;
    #pragma unroll
    for (int k = 0; k < 16; k++) {
      float mz = lp[k][i] + lcv[k];
      y0 += qb[(size_t)(0 * 16 + k) * NPIX + n] * mz;
      y1 += qb[(size_t)(1 * 16 + k) * NPIX + n] * mz;
      y2 += qb[(size_t)(2 * 16 + k) * NPIX + n] * mz;
      y3 += qb[(size_t)(3 * 16 + k) * NPIX + n] * mz;
    }
    ob[(size_t)(0 * 64 + v) * NPIX + n] = y0;
    ob[(size_t)(1 * 64 + v) * NPIX + n] = y1;
    ob[(size_t)(2 * 64 + v) * NPIX + n] = y2;
    ob[(size_t)(3 * 64 + v) * NPIX + n] = y3;
  }
}

extern "C" void kernel_launch(void* const* d_in, const int* in_sizes, int n_in,
                              void* d_out, int out_size, void* d_ws, size_t ws_size,
                              hipStream_t stream) {
  const float* x    = (const float*)d_in[0];
  const float* Wq   = (const float*)d_in[1];
  const float* qg   = (const float*)d_in[2];
  const float* qbta = (const float*)d_in[3];
  const float* qm   = (const float*)d_in[4];
  const float* qv   = (const float*)d_in[5];
  const float* Wk   = (const float*)d_in[6];
  const float* Wv   = (const float*)d_in[7];
  const float* vg   = (const float*)d_in[8];
  const float* vb   = (const float*)d_in[9];
  const float* vm   = (const float*)d_in[10];
  const float* vvar = (const float*)d_in[11];
  const float* emb  = (const float*)d_in[12];
  float* ws   = (float*)d_ws;
  float* Wp   = ws + WP_OFF;
  float* bp   = ws + BIAS_OFF;
  float* proj = ws + PROJ_OFF;
  float* rmax = ws + RMAX_OFF;
  float* rsc  = ws + RSC_OFF;
  float* lcw  = ws + LC_OFF;
  float* out  = (float*)d_out;

  hipLaunchKernelGGL(k_wfold, dim3(144), dim3(256), 0, stream,
                     Wq, qg, qbta, qm, qv, Wk, Wv, vg, vb, vm, vvar, Wp, bp);
  hipLaunchKernelGGL(k_proj, dim3(9, 16, 8), dim3(256), 0, stream, x, Wp, bp, proj);
  hipLaunchKernelGGL(k_softstat, dim3(16, 8), dim3(256), 0, stream, proj, rmax, rsc);
  hipLaunchKernelGGL(k_lambda_c, dim3(16, 8), dim3(256), 0, stream, proj, rmax, rsc, lcw);
  hipLaunchKernelGGL(k_conv_fused, dim3(64, 4, 8), dim3(256), 0, stream, proj, emb, lcw, out);
}